// Round 3
// baseline (330.135 us; speedup 1.0000x reference)
//
#include <hip/hip_runtime.h>
#include <cstdint>

#define K_NE 16
constexpr int B = 8, N = 2048, F = 128;
constexpr size_t NSEND = (size_t)B * N;                 // 16384 sender rows
constexpr size_t EDGE_FLOATS = NSEND * K_NE * 256;      // 67,108,864
constexpr size_t SEND_FLOATS = (size_t)B * N * N;       // 33,554,432

// ---------------- K0: row norms (one wave per 128-float row) ----------------
__global__ __launch_bounds__(256) void norms_kernel(const float* __restrict__ X,
                                                    float* __restrict__ out) {
    int tid = blockIdx.x * 256 + threadIdx.x;
    int w = tid >> 6, lane = tid & 63;
    const float2 v = ((const float2*)(X + (size_t)w * F))[lane];
    float s = v.x * v.x + v.y * v.y;
    #pragma unroll
    for (int off = 32; off; off >>= 1) s += __shfl_xor(s, off);
    if (lane == 0) out[w] = s;
}

// ---------------- K1: score matrix  dist[b][s][r] = |x2+y2-2*dot| -----------
// 128x128 block tile, 256 threads, 8x8 micro-tile (2x2 of float4),
// K-major LDS [BK=8][128] so fragment reads are conflict-free (2-way max).
__global__ __launch_bounds__(256) void score_kernel(const float* __restrict__ S,
                                                    const float* __restrict__ Rv,
                                                    const float* __restrict__ x2,
                                                    const float* __restrict__ y2,
                                                    float* __restrict__ scores) {
    __shared__ float As[8][128];   // [k][row]  (A = senders)
    __shared__ float Bs[8][128];   // [k][col]  (B = receivers)
    const int bx = blockIdx.x, by = blockIdx.y, bz = blockIdx.z;
    const int t = threadIdx.x;
    const int tx = t & 15, ty = t >> 4;          // 16x16 thread grid
    const float* Sb = S  + (size_t)bz * N * F + (size_t)by * 128 * F;
    const float* Rb = Rv + (size_t)bz * N * F + (size_t)bx * 128 * F;

    const int srow = t >> 1;            // 0..127
    const int skq  = (t & 1) << 2;      // 0 or 4 (k-quad within BK=8)

    float acc[8][8] = {};

    for (int kc = 0; kc < 16; ++kc) {   // 16 chunks of BK=8 over K=128
        const float4 a = *(const float4*)(Sb + (size_t)srow * F + (kc << 3) + skq);
        const float4 b = *(const float4*)(Rb + (size_t)srow * F + (kc << 3) + skq);
        __syncthreads();   // previous chunk's reads done before overwrite
        As[skq + 0][srow] = a.x; As[skq + 1][srow] = a.y;
        As[skq + 2][srow] = a.z; As[skq + 3][srow] = a.w;
        Bs[skq + 0][srow] = b.x; Bs[skq + 1][srow] = b.y;
        Bs[skq + 2][srow] = b.z; Bs[skq + 3][srow] = b.w;
        __syncthreads();
        #pragma unroll
        for (int k = 0; k < 8; ++k) {
            float4 a0 = *(const float4*)(&As[k][ty * 4]);
            float4 a1 = *(const float4*)(&As[k][64 + ty * 4]);
            float4 b0 = *(const float4*)(&Bs[k][tx * 4]);
            float4 b1 = *(const float4*)(&Bs[k][64 + tx * 4]);
            float av[8] = {a0.x, a0.y, a0.z, a0.w, a1.x, a1.y, a1.z, a1.w};
            float bv[8] = {b0.x, b0.y, b0.z, b0.w, b1.x, b1.y, b1.z, b1.w};
            #pragma unroll
            for (int i = 0; i < 8; ++i)
                #pragma unroll
                for (int j = 0; j < 8; ++j)
                    acc[i][j] = fmaf(av[i], bv[j], acc[i][j]);
        }
    }

    float* outb = scores + (size_t)bz * N * N;
    const float* x2b = x2 + (size_t)bz * N;
    const float* y2b = y2 + (size_t)bz * N;
    float yv[8];
    #pragma unroll
    for (int c = 0; c < 4; ++c) {
        yv[c]     = y2b[bx * 128 + tx * 4 + c];
        yv[4 + c] = y2b[bx * 128 + 64 + tx * 4 + c];
    }
    #pragma unroll
    for (int i = 0; i < 8; ++i) {
        const int r = by * 128 + ty * 4 + (i & 3) + 64 * (i >> 2);
        const float xv = x2b[r];
        float* orow = outb + (size_t)r * N + bx * 128;
        float4 o0, o1;
        o0.x = fabsf((-2.0f * acc[i][0] + xv) + yv[0]);
        o0.y = fabsf((-2.0f * acc[i][1] + xv) + yv[1]);
        o0.z = fabsf((-2.0f * acc[i][2] + xv) + yv[2]);
        o0.w = fabsf((-2.0f * acc[i][3] + xv) + yv[3]);
        o1.x = fabsf((-2.0f * acc[i][4] + xv) + yv[4]);
        o1.y = fabsf((-2.0f * acc[i][5] + xv) + yv[5]);
        o1.z = fabsf((-2.0f * acc[i][6] + xv) + yv[6]);
        o1.w = fabsf((-2.0f * acc[i][7] + xv) + yv[7]);
        *(float4*)(orow + tx * 4)      = o0;
        *(float4*)(orow + 64 + tx * 4) = o1;
    }
}

// ---------------- K2: top-16 per sender row, ascending-index emit -----------
__global__ __launch_bounds__(256) void topk_kernel(const float* __restrict__ scores,
                                                   int* __restrict__ idxb) {
    const int t = threadIdx.x;
    const int lane = t & 63;
    const int row = blockIdx.x * 4 + (t >> 6);   // global sender id
    const float* sr = scores + (size_t)row * N;
    float c[32], w[32];
    #pragma unroll
    for (int j = 0; j < 32; ++j) { c[j] = sr[(j << 6) + lane]; w[j] = c[j]; }
    float T = 0.0f;
    for (int it = 0; it < 16; ++it) {
        float bv = w[0]; int bi = lane;
        #pragma unroll
        for (int j = 1; j < 32; ++j) {
            int idx = (j << 6) + lane;
            if (w[j] < bv) { bv = w[j]; bi = idx; }
        }
        #pragma unroll
        for (int off = 32; off; off >>= 1) {
            float ov = __shfl_xor(bv, off);
            int   oi = __shfl_xor(bi, off);
            if (ov < bv || (ov == bv && oi < bi)) { bv = ov; bi = oi; }
        }
        T = bv;
        int jj = bi >> 6;
        bool mine = (bi & 63) == lane;
        #pragma unroll
        for (int j = 0; j < 32; ++j)
            if (mine && jj == j) w[j] = __builtin_inff();
    }
    int m = 0;
    #pragma unroll
    for (int j = 0; j < 32; ++j) m += __popcll(__ballot(c[j] < T));
    const int quota = K_NE - m;
    const unsigned long long lt = (1ull << lane) - 1ull;
    int emitted = 0, eqc = 0;
    int* ob = idxb + row * K_NE;
    #pragma unroll
    for (int j = 0; j < 32; ++j) {
        float v = c[j];
        int idx = (j << 6) + lane;
        unsigned long long em = __ballot(v == T);
        int eq_rank = eqc + __popcll(em & lt);
        bool acc = (v < T) || ((v == T) && (eq_rank < quota));
        unsigned long long am = __ballot(acc);
        if (acc) ob[emitted + __popcll(am & lt)] = idx;
        emitted += __popcll(am);
        eqc += __popcll(em);
    }
}

// ---------------- K3: edge rows (fully coalesced float4 writes) -------------
__global__ __launch_bounds__(256) void edges_kernel(const float* __restrict__ S,
                                                    const float* __restrict__ Rv,
                                                    const int* __restrict__ idxb,
                                                    float* __restrict__ out) {
    const int g = blockIdx.x;            // sender id 0..16383
    const int t = threadIdx.x;
    __shared__ int sidx[K_NE];
    if (t < K_NE) sidx[t] = idxb[g * K_NE + t];
    __syncthreads();
    const float4* srow = (const float4*)(S + (size_t)g * F);
    const float4* rb = (const float4*)(Rv + (size_t)(g >> 11) * N * F);
    float4* ob = (float4*)(out + (size_t)g * (K_NE * 256));
    #pragma unroll
    for (int i = 0; i < 4; ++i) {
        int f = t + (i << 8);            // float4 id within the 16x256 block
        int e = f >> 6, p = f & 63;
        float4 v = (p < 32) ? srow[p] : rb[(size_t)sidx[e] * 32 + (p - 32)];
        ob[f] = v;
    }
}

// ---------------- K4: build connectivity matrix in one coalesced pass -------
// One block per sender row. Thread t owns float4 chunks t and t+256 of the
// 2048-col row; builds them in registers (zeros + compares against the 16
// sorted neighbour indices), single write stream, no memset needed.
__global__ __launch_bounds__(256) void conn_kernel(const int* __restrict__ idxb,
                                                   float* __restrict__ sm) {
    const int g = blockIdx.x;            // sender id 0..16383
    const int t = threadIdx.x;
    __shared__ int sidx[K_NE];
    if (t < K_NE) sidx[t] = idxb[g * K_NE + t];
    __syncthreads();
    float4 v0 = {0.f, 0.f, 0.f, 0.f}, v1 = {0.f, 0.f, 0.f, 0.f};
    #pragma unroll
    for (int k = 0; k < K_NE; ++k) {
        const int c = sidx[k];
        const int q = c >> 2, r = c & 3;
        if (q == t)       ((float*)&v0)[r] = 1.0f;
        if (q == t + 256) ((float*)&v1)[r] = 1.0f;
    }
    float4* orow = (float4*)(sm + (size_t)g * N);
    orow[t]       = v0;
    orow[t + 256] = v1;
}

extern "C" void kernel_launch(void* const* d_in, const int* in_sizes, int n_in,
                              void* d_out, int out_size, void* d_ws, size_t ws_size,
                              hipStream_t stream) {
    (void)in_sizes; (void)n_in; (void)out_size;
    const float* recv = (const float*)d_in[0];
    const float* send = (const float*)d_in[1];
    float* out = (float*)d_out;
    float* sender_mat = out + EDGE_FLOATS;       // also used as 128MB score scratch
    int*   idx_ws = (int*)d_ws;
    float* x2 = (float*)((char*)d_ws + (262144u * 4));
    float* y2 = x2 + NSEND;

    norms_kernel<<<4096, 256, 0, stream>>>(send, x2);
    norms_kernel<<<4096, 256, 0, stream>>>(recv, y2);
    dim3 g1(16, 16, 8);
    score_kernel<<<g1, 256, 0, stream>>>(send, recv, x2, y2, sender_mat);
    topk_kernel<<<4096, 256, 0, stream>>>(sender_mat, idx_ws);
    edges_kernel<<<16384, 256, 0, stream>>>(send, recv, idx_ws, out);
    conn_kernel<<<16384, 256, 0, stream>>>(idx_ws, sender_mat);
}

// Round 4
// 301.707 us; speedup vs baseline: 1.0942x; 1.0942x over previous
//
#include <hip/hip_runtime.h>
#include <cstdint>

#define K_NE 16
constexpr int B = 8, N = 2048, F = 128;
constexpr size_t NSEND = (size_t)B * N;                 // 16384 sender rows
constexpr size_t EDGE_FLOATS = NSEND * K_NE * 256;      // 67,108,864
constexpr size_t SEND_FLOATS = (size_t)B * N * N;       // 33,554,432

// ---------------- K0: row norms (one wave per 128-float row) ----------------
__global__ __launch_bounds__(256) void norms_kernel(const float* __restrict__ X,
                                                    float* __restrict__ out) {
    int tid = blockIdx.x * 256 + threadIdx.x;
    int w = tid >> 6, lane = tid & 63;
    const float2 v = ((const float2*)(X + (size_t)w * F))[lane];
    float s = v.x * v.x + v.y * v.y;
    #pragma unroll
    for (int off = 32; off; off >>= 1) s += __shfl_xor(s, off);
    if (lane == 0) out[w] = s;
}

// ---------------- K1: score matrix  dist[b][s][r] = |x2+y2-2*dot| -----------
// 128x128 block tile, 256 threads, 8x8 micro-tile, BK=16 k-major LDS,
// global->reg prefetch of next chunk pipelined under compute.
// NOTE: per-(i,j) accumulation is a single FMA chain over k=0..127 ascending
// -> bitwise-identical to previous passing version (selection preserved).
__global__ __launch_bounds__(256, 4) void score_kernel(const float* __restrict__ S,
                                                       const float* __restrict__ Rv,
                                                       const float* __restrict__ x2,
                                                       const float* __restrict__ y2,
                                                       float* __restrict__ scores) {
    __shared__ float As[16][128];   // [k][row]  (A = senders)
    __shared__ float Bs[16][128];   // [k][col]  (B = receivers)
    const int bx = blockIdx.x, by = blockIdx.y, bz = blockIdx.z;
    const int t = threadIdx.x;
    const int tx = t & 15, ty = t >> 4;          // 16x16 thread grid
    const float* Sb = S  + (size_t)bz * N * F + (size_t)by * 128 * F;
    const float* Rb = Rv + (size_t)bz * N * F + (size_t)bx * 128 * F;

    const int srow = t >> 1;            // 0..127
    const int koff = (t & 1) << 3;      // 0 or 8
    const float* pa = Sb + (size_t)srow * F + koff;
    const float* pb = Rb + (size_t)srow * F + koff;

    float4 a0 = *(const float4*)(pa);
    float4 a1 = *(const float4*)(pa + 4);
    float4 b0 = *(const float4*)(pb);
    float4 b1 = *(const float4*)(pb + 4);

    float acc[8][8] = {};

    for (int kc = 0; kc < 8; ++kc) {    // 8 chunks of BK=16
        __syncthreads();                // previous chunk's reads done
        As[koff + 0][srow] = a0.x; As[koff + 1][srow] = a0.y;
        As[koff + 2][srow] = a0.z; As[koff + 3][srow] = a0.w;
        As[koff + 4][srow] = a1.x; As[koff + 5][srow] = a1.y;
        As[koff + 6][srow] = a1.z; As[koff + 7][srow] = a1.w;
        Bs[koff + 0][srow] = b0.x; Bs[koff + 1][srow] = b0.y;
        Bs[koff + 2][srow] = b0.z; Bs[koff + 3][srow] = b0.w;
        Bs[koff + 4][srow] = b1.x; Bs[koff + 5][srow] = b1.y;
        Bs[koff + 6][srow] = b1.z; Bs[koff + 7][srow] = b1.w;
        __syncthreads();
        if (kc < 7) {                   // prefetch next chunk (latency hidden)
            const int o = (kc + 1) << 4;
            a0 = *(const float4*)(pa + o);
            a1 = *(const float4*)(pa + o + 4);
            b0 = *(const float4*)(pb + o);
            b1 = *(const float4*)(pb + o + 4);
        }
        #pragma unroll
        for (int k = 0; k < 16; ++k) {
            float4 af0 = *(const float4*)(&As[k][ty * 4]);
            float4 af1 = *(const float4*)(&As[k][64 + ty * 4]);
            float4 bf0 = *(const float4*)(&Bs[k][tx * 4]);
            float4 bf1 = *(const float4*)(&Bs[k][64 + tx * 4]);
            float av[8] = {af0.x, af0.y, af0.z, af0.w, af1.x, af1.y, af1.z, af1.w};
            float bv[8] = {bf0.x, bf0.y, bf0.z, bf0.w, bf1.x, bf1.y, bf1.z, bf1.w};
            #pragma unroll
            for (int i = 0; i < 8; ++i)
                #pragma unroll
                for (int j = 0; j < 8; ++j)
                    acc[i][j] = fmaf(av[i], bv[j], acc[i][j]);
        }
    }

    float* outb = scores + (size_t)bz * N * N;
    const float* x2b = x2 + (size_t)bz * N;
    const float* y2b = y2 + (size_t)bz * N;
    float yv[8];
    #pragma unroll
    for (int c = 0; c < 4; ++c) {
        yv[c]     = y2b[bx * 128 + tx * 4 + c];
        yv[4 + c] = y2b[bx * 128 + 64 + tx * 4 + c];
    }
    #pragma unroll
    for (int i = 0; i < 8; ++i) {
        const int r = by * 128 + ty * 4 + (i & 3) + 64 * (i >> 2);
        const float xv = x2b[r];
        float* orow = outb + (size_t)r * N + bx * 128;
        float4 o0, o1;
        o0.x = fabsf((-2.0f * acc[i][0] + xv) + yv[0]);
        o0.y = fabsf((-2.0f * acc[i][1] + xv) + yv[1]);
        o0.z = fabsf((-2.0f * acc[i][2] + xv) + yv[2]);
        o0.w = fabsf((-2.0f * acc[i][3] + xv) + yv[3]);
        o1.x = fabsf((-2.0f * acc[i][4] + xv) + yv[4]);
        o1.y = fabsf((-2.0f * acc[i][5] + xv) + yv[5]);
        o1.z = fabsf((-2.0f * acc[i][6] + xv) + yv[6]);
        o1.w = fabsf((-2.0f * acc[i][7] + xv) + yv[7]);
        *(float4*)(orow + tx * 4)      = o0;
        *(float4*)(orow + 64 + tx * 4) = o1;
    }
}

// ---------------- K2: top-16 per sender row --------------------------------
// One wave per row. (value,index) packed into an integer-valued double:
//   d = float_bits(v)*2048 + idx   (v >= 0 so bits are order-monotone; exact
//   in 53 bits; lexicographic min == jax stable top_k tie-break).
// Cached 4 group-mins + lane-min; per extraction: f64 butterfly + owner-only
// group rescan. Decode via 2^52 mantissa trick; emit rank-sorted by index.
#define CLRG(M, J0)                                                        \
    {                                                                      \
        _Pragma("unroll")                                                  \
        for (int j = 0; j < 8; ++j)                                        \
            d[J0 + j] = (d[J0 + j] == g) ? 1e300 : d[J0 + j];              \
        M = fmin(fmin(fmin(d[J0+0], d[J0+1]), fmin(d[J0+2], d[J0+3])),     \
                 fmin(fmin(d[J0+4], d[J0+5]), fmin(d[J0+6], d[J0+7])));    \
    }

__global__ __launch_bounds__(256) void topk_kernel(const float* __restrict__ scores,
                                                   int* __restrict__ idxb) {
    const int t = threadIdx.x;
    const int lane = t & 63;
    const int row = blockIdx.x * 4 + (t >> 6);   // global sender id
    const float4* sr = (const float4*)(scores + (size_t)row * N);

    double d[32];
    #pragma unroll
    for (int jj = 0; jj < 8; ++jj) {
        float4 v = sr[jj * 64 + lane];
        const double base = (double)(jj * 256 + lane * 4);
        d[jj * 4 + 0] = (double)__float_as_uint(v.x) * 2048.0 + (base + 0.0);
        d[jj * 4 + 1] = (double)__float_as_uint(v.y) * 2048.0 + (base + 1.0);
        d[jj * 4 + 2] = (double)__float_as_uint(v.z) * 2048.0 + (base + 2.0);
        d[jj * 4 + 3] = (double)__float_as_uint(v.w) * 2048.0 + (base + 3.0);
    }
    double m0 = fmin(fmin(fmin(d[0], d[1]), fmin(d[2], d[3])),
                     fmin(fmin(d[4], d[5]), fmin(d[6], d[7])));
    double m1 = fmin(fmin(fmin(d[8], d[9]), fmin(d[10], d[11])),
                     fmin(fmin(d[12], d[13]), fmin(d[14], d[15])));
    double m2 = fmin(fmin(fmin(d[16], d[17]), fmin(d[18], d[19])),
                     fmin(fmin(d[20], d[21]), fmin(d[22], d[23])));
    double m3 = fmin(fmin(fmin(d[24], d[25]), fmin(d[26], d[27])),
                     fmin(fmin(d[28], d[29]), fmin(d[30], d[31])));
    double loc = fmin(fmin(m0, m1), fmin(m2, m3));

    double r16[16];
    #pragma unroll
    for (int it = 0; it < 16; ++it) {
        double g = loc;
        #pragma unroll
        for (int off = 32; off; off >>= 1) g = fmin(g, __shfl_xor(g, off));
        r16[it] = g;
        if (loc == g) {                 // single owner lane (d values unique)
            if      (m0 == g) CLRG(m0, 0)
            else if (m1 == g) CLRG(m1, 8)
            else if (m2 == g) CLRG(m2, 16)
            else              CLRG(m3, 24)
            loc = fmin(fmin(m0, m1), fmin(m2, m3));
        }
    }

    const double MAGIC = 4503599627370496.0;     // 2^52
    int x = 0;
    #pragma unroll
    for (int it = 0; it < 16; ++it) {
        int ix = (int)(__double_as_longlong(r16[it] + MAGIC) & 2047);
        if (lane == it) x = ix;
    }
    int rank = 0;
    #pragma unroll
    for (int it = 0; it < 16; ++it) {
        int ix = (int)(__double_as_longlong(r16[it] + MAGIC) & 2047);
        rank += (ix < x) ? 1 : 0;
    }
    if (lane < 16) idxb[row * K_NE + rank] = x;
}

// ---------------- K3: edge rows (fully coalesced float4 writes) -------------
__global__ __launch_bounds__(256) void edges_kernel(const float* __restrict__ S,
                                                    const float* __restrict__ Rv,
                                                    const int* __restrict__ idxb,
                                                    float* __restrict__ out) {
    const int g = blockIdx.x;            // sender id 0..16383
    const int t = threadIdx.x;
    __shared__ int sidx[K_NE];
    if (t < K_NE) sidx[t] = idxb[g * K_NE + t];
    __syncthreads();
    const float4* srow = (const float4*)(S + (size_t)g * F);
    const float4* rb = (const float4*)(Rv + (size_t)(g >> 11) * N * F);
    float4* ob = (float4*)(out + (size_t)g * (K_NE * 256));
    #pragma unroll
    for (int i = 0; i < 4; ++i) {
        int f = t + (i << 8);            // float4 id within the 16x256 block
        int e = f >> 6, p = f & 63;
        float4 v = (p < 32) ? srow[p] : rb[(size_t)sidx[e] * 32 + (p - 32)];
        ob[f] = v;
    }
}

// ---------------- K4: build connectivity matrix in one coalesced pass -------
__global__ __launch_bounds__(256) void conn_kernel(const int* __restrict__ idxb,
                                                   float* __restrict__ sm) {
    const int g = blockIdx.x;            // sender id 0..16383
    const int t = threadIdx.x;
    __shared__ int sidx[K_NE];
    if (t < K_NE) sidx[t] = idxb[g * K_NE + t];
    __syncthreads();
    float4 v0 = {0.f, 0.f, 0.f, 0.f}, v1 = {0.f, 0.f, 0.f, 0.f};
    #pragma unroll
    for (int k = 0; k < K_NE; ++k) {
        const int c = sidx[k];
        const int q = c >> 2, r = c & 3;
        if (q == t)       ((float*)&v0)[r] = 1.0f;
        if (q == t + 256) ((float*)&v1)[r] = 1.0f;
    }
    float4* orow = (float4*)(sm + (size_t)g * N);
    orow[t]       = v0;
    orow[t + 256] = v1;
}

extern "C" void kernel_launch(void* const* d_in, const int* in_sizes, int n_in,
                              void* d_out, int out_size, void* d_ws, size_t ws_size,
                              hipStream_t stream) {
    (void)in_sizes; (void)n_in; (void)out_size;
    const float* recv = (const float*)d_in[0];
    const float* send = (const float*)d_in[1];
    float* out = (float*)d_out;
    float* sender_mat = out + EDGE_FLOATS;       // also used as 128MB score scratch
    int*   idx_ws = (int*)d_ws;
    float* x2 = (float*)((char*)d_ws + (262144u * 4));
    float* y2 = x2 + NSEND;

    norms_kernel<<<4096, 256, 0, stream>>>(send, x2);
    norms_kernel<<<4096, 256, 0, stream>>>(recv, y2);
    dim3 g1(16, 16, 8);
    score_kernel<<<g1, 256, 0, stream>>>(send, recv, x2, y2, sender_mat);
    topk_kernel<<<4096, 256, 0, stream>>>(sender_mat, idx_ws);
    edges_kernel<<<16384, 256, 0, stream>>>(send, recv, idx_ws, out);
    conn_kernel<<<16384, 256, 0, stream>>>(idx_ws, sender_mat);
}

// Round 5
// 289.453 us; speedup vs baseline: 1.1405x; 1.0423x over previous
//
#include <hip/hip_runtime.h>
#include <cstdint>

#define K_NE 16
constexpr int B = 8, N = 2048, F = 128;
constexpr size_t NSEND = (size_t)B * N;                 // 16384 sender rows
constexpr size_t EDGE_FLOATS = NSEND * K_NE * 256;      // 67,108,864
constexpr size_t SEND_FLOATS = (size_t)B * N * N;       // 33,554,432

// ---------------- K0: row norms (one wave per 128-float row) ----------------
__global__ __launch_bounds__(256) void norms_kernel(const float* __restrict__ X,
                                                    float* __restrict__ out) {
    int tid = blockIdx.x * 256 + threadIdx.x;
    int w = tid >> 6, lane = tid & 63;
    const float2 v = ((const float2*)(X + (size_t)w * F))[lane];
    float s = v.x * v.x + v.y * v.y;
    #pragma unroll
    for (int off = 32; off; off >>= 1) s += __shfl_xor(s, off);
    if (lane == 0) out[w] = s;
}

// ---------------- K1: score matrix  dist[b][s][r] = |x2+y2-2*dot| -----------
// 128x128 tile, 256 threads, 8x8 micro-tile, BK=8 k-major LDS,
// DOUBLE-BUFFERED (one barrier per chunk) + register prefetch.
// Per-(i,j) accumulation: single fmaf chain, k ascending -> bit-identical
// to the round-2 passing version (selection preserved).
__global__ __launch_bounds__(256) void score_kernel(const float* __restrict__ S,
                                                    const float* __restrict__ Rv,
                                                    const float* __restrict__ x2,
                                                    const float* __restrict__ y2,
                                                    float* __restrict__ scores) {
    __shared__ float As[2][8][128];   // [buf][k][row]
    __shared__ float Bs[2][8][128];   // [buf][k][col]
    const int bx = blockIdx.x, by = blockIdx.y, bz = blockIdx.z;
    const int t = threadIdx.x;
    const int tx = t & 15, ty = t >> 4;
    const float* Sb = S  + (size_t)bz * N * F + (size_t)by * 128 * F;
    const float* Rb = Rv + (size_t)bz * N * F + (size_t)bx * 128 * F;

    const int srow = t >> 1;            // 0..127
    const int skq  = (t & 1) << 2;      // 0 or 4
    const float* pa = Sb + (size_t)srow * F + skq;
    const float* pb = Rb + (size_t)srow * F + skq;

    float4 a = *(const float4*)(pa);
    float4 b = *(const float4*)(pb);
    As[0][skq + 0][srow] = a.x; As[0][skq + 1][srow] = a.y;
    As[0][skq + 2][srow] = a.z; As[0][skq + 3][srow] = a.w;
    Bs[0][skq + 0][srow] = b.x; Bs[0][skq + 1][srow] = b.y;
    Bs[0][skq + 2][srow] = b.z; Bs[0][skq + 3][srow] = b.w;
    __syncthreads();

    float acc[8][8] = {};

    for (int kc = 0; kc < 16; ++kc) {   // 16 chunks of BK=8
        const int cur = kc & 1;
        if (kc < 15) {                  // issue next chunk's loads early
            a = *(const float4*)(pa + ((kc + 1) << 3));
            b = *(const float4*)(pb + ((kc + 1) << 3));
        }
        #pragma unroll
        for (int k = 0; k < 8; ++k) {
            const float4 af0 = *(const float4*)(&As[cur][k][ty * 4]);
            const float4 af1 = *(const float4*)(&As[cur][k][64 + ty * 4]);
            const float4 bf0 = *(const float4*)(&Bs[cur][k][tx * 4]);
            const float4 bf1 = *(const float4*)(&Bs[cur][k][64 + tx * 4]);
            const float av[8] = {af0.x, af0.y, af0.z, af0.w, af1.x, af1.y, af1.z, af1.w};
            const float bv[8] = {bf0.x, bf0.y, bf0.z, bf0.w, bf1.x, bf1.y, bf1.z, bf1.w};
            #pragma unroll
            for (int i = 0; i < 8; ++i)
                #pragma unroll
                for (int j = 0; j < 8; ++j)
                    acc[i][j] = fmaf(av[i], bv[j], acc[i][j]);
        }
        if (kc < 15) {
            const int nxt = cur ^ 1;    // write next buffer; one barrier/chunk
            As[nxt][skq + 0][srow] = a.x; As[nxt][skq + 1][srow] = a.y;
            As[nxt][skq + 2][srow] = a.z; As[nxt][skq + 3][srow] = a.w;
            Bs[nxt][skq + 0][srow] = b.x; Bs[nxt][skq + 1][srow] = b.y;
            Bs[nxt][skq + 2][srow] = b.z; Bs[nxt][skq + 3][srow] = b.w;
            __syncthreads();
        }
    }

    float* outb = scores + (size_t)bz * N * N;
    const float* x2b = x2 + (size_t)bz * N;
    const float* y2b = y2 + (size_t)bz * N;
    float yv[8];
    #pragma unroll
    for (int c = 0; c < 4; ++c) {
        yv[c]     = y2b[bx * 128 + tx * 4 + c];
        yv[4 + c] = y2b[bx * 128 + 64 + tx * 4 + c];
    }
    #pragma unroll
    for (int i = 0; i < 8; ++i) {
        const int r = by * 128 + ty * 4 + (i & 3) + 64 * (i >> 2);
        const float xv = x2b[r];
        float* orow = outb + (size_t)r * N + bx * 128;
        float4 o0, o1;
        o0.x = fabsf((-2.0f * acc[i][0] + xv) + yv[0]);
        o0.y = fabsf((-2.0f * acc[i][1] + xv) + yv[1]);
        o0.z = fabsf((-2.0f * acc[i][2] + xv) + yv[2]);
        o0.w = fabsf((-2.0f * acc[i][3] + xv) + yv[3]);
        o1.x = fabsf((-2.0f * acc[i][4] + xv) + yv[4]);
        o1.y = fabsf((-2.0f * acc[i][5] + xv) + yv[5]);
        o1.z = fabsf((-2.0f * acc[i][6] + xv) + yv[6]);
        o1.w = fabsf((-2.0f * acc[i][7] + xv) + yv[7]);
        *(float4*)(orow + tx * 4)      = o0;
        *(float4*)(orow + 64 + tx * 4) = o1;
    }
}

// ------- K2: top-16 per row + idx emit + in-place connectivity row ----------
// One wave per row. (value,index) packed into an integer-valued double:
//   d = float_bits(v)*2048 + idx  (exact in 53 bits; lexicographic min ==
//   jax stable top_k tie-break). After extraction the wave OVERWRITES its
//   own score row with the 0/1 connectivity row (row g -> row g, no hazard).
#define CLRG(M, J0)                                                        \
    {                                                                      \
        _Pragma("unroll")                                                  \
        for (int j = 0; j < 8; ++j)                                        \
            d[J0 + j] = (d[J0 + j] == g) ? 1e300 : d[J0 + j];              \
        M = fmin(fmin(fmin(d[J0+0], d[J0+1]), fmin(d[J0+2], d[J0+3])),     \
                 fmin(fmin(d[J0+4], d[J0+5]), fmin(d[J0+6], d[J0+7])));    \
    }

__global__ __launch_bounds__(256) void topk_conn_kernel(float* __restrict__ scores,
                                                        int* __restrict__ idxb) {
    const int t = threadIdx.x;
    const int lane = t & 63;
    const int row = blockIdx.x * 4 + (t >> 6);   // global sender id
    float* srowp = scores + (size_t)row * N;
    const float4* sr = (const float4*)srowp;

    double d[32];
    #pragma unroll
    for (int jj = 0; jj < 8; ++jj) {
        float4 v = sr[jj * 64 + lane];
        const double base = (double)(jj * 256 + lane * 4);
        d[jj * 4 + 0] = (double)__float_as_uint(v.x) * 2048.0 + (base + 0.0);
        d[jj * 4 + 1] = (double)__float_as_uint(v.y) * 2048.0 + (base + 1.0);
        d[jj * 4 + 2] = (double)__float_as_uint(v.z) * 2048.0 + (base + 2.0);
        d[jj * 4 + 3] = (double)__float_as_uint(v.w) * 2048.0 + (base + 3.0);
    }
    double m0 = fmin(fmin(fmin(d[0], d[1]), fmin(d[2], d[3])),
                     fmin(fmin(d[4], d[5]), fmin(d[6], d[7])));
    double m1 = fmin(fmin(fmin(d[8], d[9]), fmin(d[10], d[11])),
                     fmin(fmin(d[12], d[13]), fmin(d[14], d[15])));
    double m2 = fmin(fmin(fmin(d[16], d[17]), fmin(d[18], d[19])),
                     fmin(fmin(d[20], d[21]), fmin(d[22], d[23])));
    double m3 = fmin(fmin(fmin(d[24], d[25]), fmin(d[26], d[27])),
                     fmin(fmin(d[28], d[29]), fmin(d[30], d[31])));
    double loc = fmin(fmin(m0, m1), fmin(m2, m3));

    const double MAGIC = 4503599627370496.0;     // 2^52
    int ixs[16];
    #pragma unroll
    for (int it = 0; it < 16; ++it) {
        double g = loc;
        #pragma unroll
        for (int off = 32; off; off >>= 1) g = fmin(g, __shfl_xor(g, off));
        ixs[it] = (int)(__double_as_longlong(g + MAGIC) & 2047);  // decode now
        if (loc == g) {                 // single owner lane (d values unique)
            if      (m0 == g) CLRG(m0, 0)
            else if (m1 == g) CLRG(m1, 8)
            else if (m2 == g) CLRG(m2, 16)
            else              CLRG(m3, 24)
            loc = fmin(fmin(m0, m1), fmin(m2, m3));
        }
    }

    // emit indices rank-sorted ascending (tf.boolean_mask order)
    int x = 0;
    #pragma unroll
    for (int it = 0; it < 16; ++it)
        if (lane == it) x = ixs[it];
    int rank = 0;
    #pragma unroll
    for (int it = 0; it < 16; ++it)
        rank += (ixs[it] < x) ? 1 : 0;
    if (lane < 16) idxb[row * K_NE + rank] = x;

    // overwrite this row with the 0/1 connectivity row (coalesced float4)
    #pragma unroll
    for (int j = 0; j < 8; ++j) {
        const int c0 = j * 256 + lane * 4;
        float4 v = {0.f, 0.f, 0.f, 0.f};
        #pragma unroll
        for (int k2 = 0; k2 < 16; ++k2) {
            const int dcol = ixs[k2] - c0;
            if      (dcol == 0) v.x = 1.f;
            else if (dcol == 1) v.y = 1.f;
            else if (dcol == 2) v.z = 1.f;
            else if (dcol == 3) v.w = 1.f;
        }
        *(float4*)(srowp + c0) = v;
    }
}

// ---------------- K3: edge rows (fully coalesced float4 writes) -------------
__global__ __launch_bounds__(256) void edges_kernel(const float* __restrict__ S,
                                                    const float* __restrict__ Rv,
                                                    const int* __restrict__ idxb,
                                                    float* __restrict__ out) {
    const int g = blockIdx.x;            // sender id 0..16383
    const int t = threadIdx.x;
    __shared__ int sidx[K_NE];
    if (t < K_NE) sidx[t] = idxb[g * K_NE + t];
    __syncthreads();
    const float4* srow = (const float4*)(S + (size_t)g * F);
    const float4* rb = (const float4*)(Rv + (size_t)(g >> 11) * N * F);
    float4* ob = (float4*)(out + (size_t)g * (K_NE * 256));
    #pragma unroll
    for (int i = 0; i < 4; ++i) {
        int f = t + (i << 8);            // float4 id within the 16x256 block
        int e = f >> 6, p = f & 63;
        float4 v = (p < 32) ? srow[p] : rb[(size_t)sidx[e] * 32 + (p - 32)];
        ob[f] = v;
    }
}

extern "C" void kernel_launch(void* const* d_in, const int* in_sizes, int n_in,
                              void* d_out, int out_size, void* d_ws, size_t ws_size,
                              hipStream_t stream) {
    (void)in_sizes; (void)n_in; (void)out_size;
    const float* recv = (const float*)d_in[0];
    const float* send = (const float*)d_in[1];
    float* out = (float*)d_out;
    float* sender_mat = out + EDGE_FLOATS;       // score scratch, then conn matrix
    int*   idx_ws = (int*)d_ws;
    float* x2 = (float*)((char*)d_ws + (262144u * 4));
    float* y2 = x2 + NSEND;

    norms_kernel<<<4096, 256, 0, stream>>>(send, x2);
    norms_kernel<<<4096, 256, 0, stream>>>(recv, y2);
    dim3 g1(16, 16, 8);
    score_kernel<<<g1, 256, 0, stream>>>(send, recv, x2, y2, sender_mat);
    topk_conn_kernel<<<4096, 256, 0, stream>>>(sender_mat, idx_ws);
    edges_kernel<<<16384, 256, 0, stream>>>(send, recv, idx_ws, out);
}

// Round 6
// 229.479 us; speedup vs baseline: 1.4386x; 1.2614x over previous
//
#include <hip/hip_runtime.h>
#include <cstdint>

#define K_NE 16
constexpr int B = 8, N = 2048, F = 128;
constexpr size_t NSEND = (size_t)B * N;                 // 16384 sender rows
constexpr size_t EDGE_FLOATS = NSEND * K_NE * 256;      // 67,108,864
constexpr size_t SEND_FLOATS = (size_t)B * N * N;       // 33,554,432

// ---------------- K0: row norms (one wave per 128-float row) ----------------
__global__ __launch_bounds__(256) void norms_kernel(const float* __restrict__ X,
                                                    float* __restrict__ out) {
    int tid = blockIdx.x * 256 + threadIdx.x;
    int w = tid >> 6, lane = tid & 63;
    const float2 v = ((const float2*)(X + (size_t)w * F))[lane];
    float s = v.x * v.x + v.y * v.y;
    #pragma unroll
    for (int off = 32; off; off >>= 1) s += __shfl_xor(s, off);
    if (lane == 0) out[w] = s;
}

// ---------------- K1: score matrix  dist[b][s][r] = |x2+y2-2*dot| -----------
// UNCHANGED from round 5 (bit-identical scores -> selection preserved).
__global__ __launch_bounds__(256) void score_kernel(const float* __restrict__ S,
                                                    const float* __restrict__ Rv,
                                                    const float* __restrict__ x2,
                                                    const float* __restrict__ y2,
                                                    float* __restrict__ scores) {
    __shared__ float As[2][8][128];   // [buf][k][row]
    __shared__ float Bs[2][8][128];   // [buf][k][col]
    const int bx = blockIdx.x, by = blockIdx.y, bz = blockIdx.z;
    const int t = threadIdx.x;
    const int tx = t & 15, ty = t >> 4;
    const float* Sb = S  + (size_t)bz * N * F + (size_t)by * 128 * F;
    const float* Rb = Rv + (size_t)bz * N * F + (size_t)bx * 128 * F;

    const int srow = t >> 1;            // 0..127
    const int skq  = (t & 1) << 2;      // 0 or 4
    const float* pa = Sb + (size_t)srow * F + skq;
    const float* pb = Rb + (size_t)srow * F + skq;

    float4 a = *(const float4*)(pa);
    float4 b = *(const float4*)(pb);
    As[0][skq + 0][srow] = a.x; As[0][skq + 1][srow] = a.y;
    As[0][skq + 2][srow] = a.z; As[0][skq + 3][srow] = a.w;
    Bs[0][skq + 0][srow] = b.x; Bs[0][skq + 1][srow] = b.y;
    Bs[0][skq + 2][srow] = b.z; Bs[0][skq + 3][srow] = b.w;
    __syncthreads();

    float acc[8][8] = {};

    for (int kc = 0; kc < 16; ++kc) {   // 16 chunks of BK=8
        const int cur = kc & 1;
        if (kc < 15) {                  // issue next chunk's loads early
            a = *(const float4*)(pa + ((kc + 1) << 3));
            b = *(const float4*)(pb + ((kc + 1) << 3));
        }
        #pragma unroll
        for (int k = 0; k < 8; ++k) {
            const float4 af0 = *(const float4*)(&As[cur][k][ty * 4]);
            const float4 af1 = *(const float4*)(&As[cur][k][64 + ty * 4]);
            const float4 bf0 = *(const float4*)(&Bs[cur][k][tx * 4]);
            const float4 bf1 = *(const float4*)(&Bs[cur][k][64 + tx * 4]);
            const float av[8] = {af0.x, af0.y, af0.z, af0.w, af1.x, af1.y, af1.z, af1.w};
            const float bv[8] = {bf0.x, bf0.y, bf0.z, bf0.w, bf1.x, bf1.y, bf1.z, bf1.w};
            #pragma unroll
            for (int i = 0; i < 8; ++i)
                #pragma unroll
                for (int j = 0; j < 8; ++j)
                    acc[i][j] = fmaf(av[i], bv[j], acc[i][j]);
        }
        if (kc < 15) {
            const int nxt = cur ^ 1;    // write next buffer; one barrier/chunk
            As[nxt][skq + 0][srow] = a.x; As[nxt][skq + 1][srow] = a.y;
            As[nxt][skq + 2][srow] = a.z; As[nxt][skq + 3][srow] = a.w;
            Bs[nxt][skq + 0][srow] = b.x; Bs[nxt][skq + 1][srow] = b.y;
            Bs[nxt][skq + 2][srow] = b.z; Bs[nxt][skq + 3][srow] = b.w;
            __syncthreads();
        }
    }

    float* outb = scores + (size_t)bz * N * N;
    const float* x2b = x2 + (size_t)bz * N;
    const float* y2b = y2 + (size_t)bz * N;
    float yv[8];
    #pragma unroll
    for (int c = 0; c < 4; ++c) {
        yv[c]     = y2b[bx * 128 + tx * 4 + c];
        yv[4 + c] = y2b[bx * 128 + 64 + tx * 4 + c];
    }
    #pragma unroll
    for (int i = 0; i < 8; ++i) {
        const int r = by * 128 + ty * 4 + (i & 3) + 64 * (i >> 2);
        const float xv = x2b[r];
        float* orow = outb + (size_t)r * N + bx * 128;
        float4 o0, o1;
        o0.x = fabsf((-2.0f * acc[i][0] + xv) + yv[0]);
        o0.y = fabsf((-2.0f * acc[i][1] + xv) + yv[1]);
        o0.z = fabsf((-2.0f * acc[i][2] + xv) + yv[2]);
        o0.w = fabsf((-2.0f * acc[i][3] + xv) + yv[3]);
        o1.x = fabsf((-2.0f * acc[i][4] + xv) + yv[4]);
        o1.y = fabsf((-2.0f * acc[i][5] + xv) + yv[5]);
        o1.z = fabsf((-2.0f * acc[i][6] + xv) + yv[6]);
        o1.w = fabsf((-2.0f * acc[i][7] + xv) + yv[7]);
        *(float4*)(orow + tx * 4)      = o0;
        *(float4*)(orow + 64 + tx * 4) = o1;
    }
}

// ------- K2: fused top-16 + connectivity row + edge rows --------------------
// One wave per sender row. Row staged as u32 keys (float bits, monotone for
// v>=0) in a LANE-PRIVATE LDS slab (no barriers, no 64-VGPR live array).
// Lexicographic (key,idx) iterative min-extraction == jax stable top_k.
// Then the wave writes the 0/1 connectivity row in place of its score row,
// and its sender's 16 edge rows (ascending receiver-index order via ranks).
__global__ __launch_bounds__(256) void topk_fused_kernel(const float* __restrict__ S,
                                                         const float* __restrict__ Rv,
                                                         float* __restrict__ scores,
                                                         float* __restrict__ edges_out) {
    __shared__ uint32_t rowbuf[4][N];     // 32 KB, lane-private slices
    const int t = threadIdx.x;
    const int lane = t & 63;
    const int w = t >> 6;
    const int g = blockIdx.x * 4 + w;     // global sender id 0..16383
    const int bz = g >> 11;               // batch
    uint32_t* lds = rowbuf[w];
    float* srowp = scores + (size_t)g * N;
    const uint4* sr = (const uint4*)srowp;

    // ---- load row -> LDS keys; build per-lane (key, idx) min --------------
    uint32_t mk = 0xFFFFFFFFu, mi = 0;
    #pragma unroll
    for (int jj = 0; jj < 8; ++jj) {
        uint4 u = sr[jj * 64 + lane];
        *(uint4*)(&lds[jj * 256 + lane * 4]) = u;
        const uint32_t base = (uint32_t)(jj * 256 + lane * 4);
        if (u.x < mk) { mk = u.x; mi = base; }
        if (u.y < mk) { mk = u.y; mi = base + 1; }
        if (u.z < mk) { mk = u.z; mi = base + 2; }
        if (u.w < mk) { mk = u.w; mi = base + 3; }
    }

    // ---- 16 extractions: butterfly min + owner delete/rescan --------------
    int ixs[16];
    #pragma unroll
    for (int it = 0; it < 16; ++it) {
        const uint32_t ck = mk, ci = mi;  // pre-butterfly copy (owner test)
        uint32_t gk = mk, gi = mi;
        #pragma unroll
        for (int off = 32; off; off >>= 1) {
            uint32_t ok = (uint32_t)__shfl_xor((int)gk, off);
            uint32_t oi = (uint32_t)__shfl_xor((int)gi, off);
            if (ok < gk || (ok == gk && oi < gi)) { gk = ok; gi = oi; }
        }
        ixs[it] = (int)gi;
        if (ck == gk && ci == gi) {       // unique owner lane
            lds[gi] = 0xFFFFFFFFu;        // delete
            mk = 0xFFFFFFFFu; mi = 0;     // rescan own 32 slots
            #pragma unroll
            for (int jj = 0; jj < 8; ++jj) {
                uint4 u = *(const uint4*)(&lds[jj * 256 + lane * 4]);
                const uint32_t base = (uint32_t)(jj * 256 + lane * 4);
                if (u.x < mk) { mk = u.x; mi = base; }
                if (u.y < mk) { mk = u.y; mi = base + 1; }
                if (u.z < mk) { mk = u.z; mi = base + 2; }
                if (u.w < mk) { mk = u.w; mi = base + 3; }
            }
        }
    }

    // ---- ranks: output slot = ascending receiver-index position -----------
    int rank[16];
    #pragma unroll
    for (int e = 0; e < 16; ++e) {
        int r = 0;
        #pragma unroll
        for (int f = 0; f < 16; ++f) r += (ixs[f] < ixs[e]) ? 1 : 0;
        rank[e] = r;
    }

    // ---- connectivity row (overwrites this wave's score row) --------------
    uint32_t mask = 0;
    #pragma unroll
    for (int e = 0; e < 16; ++e) {
        const int ix = ixs[e];
        const int lane_t = (ix >> 2) & 63;
        const int bitpos = ((ix >> 8) << 2) | (ix & 3);
        if (lane == lane_t) mask |= (1u << bitpos);
    }
    #pragma unroll
    for (int j = 0; j < 8; ++j) {
        float4 v;
        v.x = (mask >> (j * 4 + 0)) & 1u ? 1.f : 0.f;
        v.y = (mask >> (j * 4 + 1)) & 1u ? 1.f : 0.f;
        v.z = (mask >> (j * 4 + 2)) & 1u ? 1.f : 0.f;
        v.w = (mask >> (j * 4 + 3)) & 1u ? 1.f : 0.f;
        *(float4*)(srowp + j * 256 + lane * 4) = v;
    }

    // ---- edge rows: [sender_feat(128) | recv_feat(128)] -------------------
    const float* srow = S + (size_t)g * F;
    const float* rb = Rv + (size_t)bz * N * F;
    float4 vs = {0.f, 0.f, 0.f, 0.f};
    if (lane < 32) vs = *(const float4*)(srow + lane * 4);
    #pragma unroll
    for (int e = 0; e < 16; ++e) {
        float4 v = vs;
        if (lane >= 32)
            v = *(const float4*)(rb + (size_t)ixs[e] * F + (lane - 32) * 4);
        *(float4*)(edges_out + ((size_t)g * K_NE + rank[e]) * 256 + lane * 4) = v;
    }
}

extern "C" void kernel_launch(void* const* d_in, const int* in_sizes, int n_in,
                              void* d_out, int out_size, void* d_ws, size_t ws_size,
                              hipStream_t stream) {
    (void)in_sizes; (void)n_in; (void)out_size; (void)ws_size;
    const float* recv = (const float*)d_in[0];
    const float* send = (const float*)d_in[1];
    float* out = (float*)d_out;
    float* sender_mat = out + EDGE_FLOATS;       // score scratch, then conn matrix
    float* x2 = (float*)((char*)d_ws + (262144u * 4));
    float* y2 = x2 + NSEND;

    norms_kernel<<<4096, 256, 0, stream>>>(send, x2);
    norms_kernel<<<4096, 256, 0, stream>>>(recv, y2);
    dim3 g1(16, 16, 8);
    score_kernel<<<g1, 256, 0, stream>>>(send, recv, x2, y2, sender_mat);
    topk_fused_kernel<<<4096, 256, 0, stream>>>(send, recv, sender_mat, out);
}